// Round 14
// baseline (410.999 us; speedup 1.0000x reference)
//
#include <hip/hip_runtime.h>

#define N_NODES 50000
#define N_EDGES 640000
#define HID 128
#define EF 16
#define NLAYERS 3
#define CHUNK 16   // MFMA M-tile: 16 edges per chunk
#define SCAN_BLOCKS 196  // ceil(50000/256)

typedef __attribute__((ext_vector_type(8))) short short8;
typedef __attribute__((ext_vector_type(8))) _Float16 half8;
typedef __attribute__((ext_vector_type(4))) float f32x4;
typedef __attribute__((ext_vector_type(2))) float f32x2;

__device__ __forceinline__ unsigned short f2bf(float f) {
  unsigned int u = __float_as_uint(f);
  u = u + 0x7FFFu + ((u >> 16) & 1u);  // RNE
  return (unsigned short)(u >> 16);
}

__device__ __forceinline__ unsigned short f2h(float f) {
  _Float16 h = (_Float16)f;
  return *(unsigned short*)&h;
}

// 8-lane butterfly sum via DPP: xor1, xor2 (quad_perm), then half-row mirror.
__device__ __forceinline__ float dpp_hadd8(float v) {
  int x;
  x = __builtin_amdgcn_update_dpp(0, __float_as_int(v), 0xB1, 0xF, 0xF, true);
  v += __int_as_float(x);
  x = __builtin_amdgcn_update_dpp(0, __float_as_int(v), 0x4E, 0xF, 0xF, true);
  v += __int_as_float(x);
  x = __builtin_amdgcn_update_dpp(0, __float_as_int(v), 0x141, 0xF, 0xF, true);
  v += __int_as_float(x);
  return v;
}

__device__ __forceinline__ f32x2 pk_add(f32x2 a, f32x2 b) {
  f32x2 d;
  asm("v_pk_add_f32 %0, %1, %2" : "=v"(d) : "v"(a), "v"(b));
  return d;
}
__device__ __forceinline__ f32x2 pk_mul(f32x2 a, f32x2 b) {
  f32x2 d;
  asm("v_pk_mul_f32 %0, %1, %2" : "=v"(d) : "v"(a), "v"(b));
  return d;
}

// channel j = h*16+c -> paired slot: lane l = h*8 + (c&7) holds halves c>>3.
__device__ __forceinline__ int pslot(int j) {
  return (((j >> 4) * 8 + (j & 7)) << 1) + ((j >> 3) & 1);
}

// Fused setup: blocks [0,26) k_prep (MtB f16 fragments + ct), [26,410) cvtw,
// [410,3535) cvtx, [3535,6035) hist (dst-degree histogram + edge rank).
__global__ __launch_bounds__(256) void k_setup(const float* __restrict__ Wt,
                                               const float* __restrict__ bt,
                                               const float* __restrict__ We,
                                               const float* __restrict__ Wl,
                                               const float* __restrict__ Wr,
                                               const float* __restrict__ x,
                                               const int* __restrict__ dst,
                                               int* __restrict__ counts,
                                               int* __restrict__ eord,
                                               float* __restrict__ ct,
                                               unsigned short* __restrict__ MtB,
                                               unsigned short* __restrict__ WT,
                                               unsigned short* __restrict__ xbf) {
  int b = blockIdx.x, t = threadIdx.x;
  if (b < 26) {
    int id = b * 256 + t;
    const int total = NLAYERS * (EF + 1) * HID;
    if (id >= total) return;
    int l = id / ((EF + 1) * HID);
    int r = id % ((EF + 1) * HID);
    int row = r / HID;
    int j = r % HID;
    const float* Wel = We + l * HID * HID;
    float s = 0.f;
    if (row < EF) {
      const float* wtr = Wt + row * HID;
      for (int i = 0; i < HID; ++i) s += wtr[i] * Wel[i * HID + j];
      // MFMA B-fragment layout for mfma_f32_16x16x32_f16:
      // lane = (k>>3)*16 + n, elem = k&7; k in [0,32) (k>=16 zero-padded).
      int blk = j >> 4, nn = j & 15;
      size_t base = (size_t)(l * 8 + blk) * 64;
      MtB[(base + (size_t)((row >> 3) * 16 + nn)) * 8 + (row & 7)] = f2h(s);
      MtB[(base + (size_t)((2 + (row >> 3)) * 16 + nn)) * 8 + (row & 7)] = 0;
    } else {
      for (int i = 0; i < HID; ++i) s += bt[i] * Wel[i * HID + j];
      ct[l * HID + pslot(j)] = s;
    }
  } else if (b < 410) {
    int id = (b - 26) * 256 + t;  // exactly NLAYERS*2*128*128 = 98304
    int k = id & (HID - 1);
    int n = (id >> 7) & (HID - 1);
    int s = (id >> 14) & 1;
    int l = id >> 15;
    const float* W = (s == 0 ? Wl : Wr) + (size_t)l * HID * HID;
    WT[id] = f2bf(W[k * HID + n]);
  } else if (b < 3535) {
    int id = (b - 410) * 256 + t;  // exactly N_NODES*HID/8 = 800000
    const float4* p = (const float4*)(x + (size_t)id * 8);
    float4 a = p[0], bb = p[1];
    unsigned short o[8] = {f2bf(a.x), f2bf(a.y), f2bf(a.z), f2bf(a.w),
                           f2bf(bb.x), f2bf(bb.y), f2bf(bb.z), f2bf(bb.w)};
    *(uint4*)(xbf + (size_t)id * 8) = *(uint4*)o;
  } else {
    int e = (b - 3535) * 256 + t;  // exactly N_EDGES = 640000
    if (e < N_EDGES) {
      int pos = atomicAdd(&counts[dst[e]], 1);
      eord[e] = pos;  // edge's rank within its dst segment (order-free)
    }
  }
}

__global__ __launch_bounds__(256) void k_scan1(const int* __restrict__ counts,
                                               int* __restrict__ rowptr,
                                               int* __restrict__ bsum) {
  __shared__ int sc[256];
  int t = threadIdx.x;
  int i = blockIdx.x * 256 + t;
  int v = (i < N_NODES) ? counts[i] : 0;
  sc[t] = v;
  __syncthreads();
  for (int off = 1; off < 256; off <<= 1) {
    int u = 0;
    if (t >= off) u = sc[t - off];
    __syncthreads();
    sc[t] += u;
    __syncthreads();
  }
  if (i < N_NODES) rowptr[i] = sc[t] - v;  // block-local exclusive
  if (t == 255) bsum[blockIdx.x] = sc[255];
}

// scan2 folded in: every block redundantly scans the 196 block sums in LDS
// (cheap) -> eliminates the fully-serializing 1-block scan2 dispatch.
__global__ __launch_bounds__(256) void k_scan3(int* __restrict__ rowptr,
                                               const int* __restrict__ bsum) {
  __shared__ int sc[256];
  int t = threadIdx.x;
  int v = (t < SCAN_BLOCKS) ? bsum[t] : 0;
  sc[t] = v;
  __syncthreads();
  for (int off = 1; off < 256; off <<= 1) {
    int u = 0;
    if (t >= off) u = sc[t - off];
    __syncthreads();
    sc[t] += u;
    __syncthreads();
  }
  int b = blockIdx.x;
  int boff = (b == 0) ? 0 : sc[b - 1];  // exclusive offset for this block
  int i = b * 256 + t;
  if (i < N_NODES) rowptr[i] += boff;
  if (i == 0) rowptr[N_NODES] = N_EDGES;
}

// Scatter edges into dst-sorted order; idx = rowptr[dst] + precomputed rank
// (NO atomics). ssrc stores src*64 (dword row offset). Emits edge_attr as
// f16 rows: eaA[idx][0..15]=f16(ea).
__global__ __launch_bounds__(256) void k_fill(const int* __restrict__ src,
                                              const int* __restrict__ dst,
                                              const int* __restrict__ rowptr,
                                              const int* __restrict__ eord,
                                              int* __restrict__ ssrc,
                                              const float* __restrict__ eattr,
                                              unsigned short* __restrict__ eaA) {
  int e = blockIdx.x * 256 + threadIdx.x;
  if (e >= N_EDGES) return;
  int d = dst[e];
  int idx = rowptr[d] + eord[e];
  ssrc[idx] = src[e] << 6;
  const float* pe = eattr + (size_t)e * EF;
  unsigned short* po = eaA + (size_t)idx * 16;
#pragma unroll
  for (int g = 0; g < 2; ++g) {
    unsigned short o[8];
#pragma unroll
    for (int k = 0; k < 8; ++k) o[k] = f2h(pe[g * 8 + k]);
    *(uint4*)(po + g * 8) = *(uint4*)o;
  }
}

// bf16 MFMA node GEMM: out_s = x @ W_s + b_s for BOTH s in one block
// (As/xbf loaded once), channel-PAIRED layout, bf16 out. s=1 folds ct.
__global__ __launch_bounds__(256) void k_gemm_mfma(const unsigned short* __restrict__ xbf,
                                                   const unsigned short* __restrict__ WTl,
                                                   const float* __restrict__ bl,
                                                   const float* __restrict__ br,
                                                   const float* __restrict__ ctl,
                                                   unsigned short* __restrict__ xlb,
                                                   unsigned short* __restrict__ xrb) {
  __shared__ short As[64 * 136];
  __shared__ short Bs[128 * 136];
  int t = threadIdx.x;
  int row0 = blockIdx.x * 64;

  const uint4* gx = (const uint4*)xbf;
#pragma unroll
  for (int p = 0; p < 4; ++p) {
    int c = t + p * 256;
    int row = c >> 4, col16 = c & 15;
    int grow = row0 + row;
    if (grow >= N_NODES) grow = N_NODES - 1;
    uint4 v = gx[grow * 16 + col16];
    *(uint4*)(&As[row * 136 + col16 * 8]) = v;
  }

  int lane = t & 63, w = t >> 6;
  int quad = lane >> 4, lm = lane & 15;
  const uint4* gw = (const uint4*)WTl;

  for (int s = 0; s < 2; ++s) {
    if (s) __syncthreads();  // all waves done with previous Bs
#pragma unroll
    for (int p = 0; p < 8; ++p) {
      int c = t + p * 256;
      int row = c >> 4, col16 = c & 15;
      uint4 v = gw[s * 2048 + row * 16 + col16];
      *(uint4*)(&Bs[row * 136 + col16 * 8]) = v;
    }
    __syncthreads();  // Bs (and As on first iter) ready

    f32x4 acc[4][2];
#pragma unroll
    for (int mf = 0; mf < 4; ++mf)
#pragma unroll
      for (int nf = 0; nf < 2; ++nf) acc[mf][nf] = (f32x4)(0.f);

#pragma unroll
    for (int ks = 0; ks < 4; ++ks) {
      short8 af[4], bf[2];
#pragma unroll
      for (int mf = 0; mf < 4; ++mf)
        af[mf] = *(short8*)(&As[(mf * 16 + lm) * 136 + ks * 32 + quad * 8]);
#pragma unroll
      for (int nf = 0; nf < 2; ++nf)
        bf[nf] = *(short8*)(&Bs[(w * 32 + nf * 16 + lm) * 136 + ks * 32 + quad * 8]);
#pragma unroll
      for (int mf = 0; mf < 4; ++mf)
#pragma unroll
        for (int nf = 0; nf < 2; ++nf)
          acc[mf][nf] = __builtin_amdgcn_mfma_f32_16x16x32_bf16(af[mf], bf[nf], acc[mf][nf], 0, 0, 0);
    }

    const float* bias = (s == 0) ? bl : br;
    unsigned short* out = (s == 0) ? xlb : xrb;
#pragma unroll
    for (int nf = 0; nf < 2; ++nf) {
      int n = w * 32 + nf * 16 + lm;
      int slot = pslot(n);
      float bv = bias[n] + ((s == 1) ? ctl[slot] : 0.f);
#pragma unroll
      for (int mf = 0; mf < 4; ++mf) {
#pragma unroll
        for (int r = 0; r < 4; ++r) {
          int grow = row0 + mf * 16 + quad * 4 + r;
          if (grow < N_NODES) out[(size_t)grow * HID + slot] = f2bf(acc[mf][nf][r] + bv);
        }
      }
    }
  }
}

// ONE WAVE per destination node, barrier-free. Lane l owns channels
// j0=(l>>3)*16+(l&7), j0+8 (same head). Per 16-edge chunk, the ea@Mt edge
// embedding is computed on the MFMA pipe (8x mfma_f32_16x16x32_f16, K
// zero-padded 16->32 in registers) and scattered into a SPLIT-HALF LDS tile
// em2[hi][row][slot] (row stride 66 dw): pair slot of lane l's j0 is exactly
// l, so the edge read is two stride-1 ds_read_b32 (2-way, free) and the
// scatter store is exact 2-way (free) -- no bank conflicts (was 3.68M cyc
// with the interleaved-pair b64 layout).
// NO src_s LDS: lane l keeps sv=ssrc[c0+l] in a register; per-edge broadcast
// via readlane -> uniform SGPR gather base (addressing on SALU pipe).
// Chunk-level pipeline: next chunk's sv + eaA A-frag prefetched under the
// current chunk's work, GATED on the wave-uniform "next chunk exists" test.
// Rolling depth-4 gather pipeline in the edge loop (best measured schedule).
__global__ __launch_bounds__(64) void k_fused(const float* __restrict__ xin,
                                              const unsigned int* __restrict__ xlb,  // paired bf16
                                              const unsigned int* __restrict__ xrb,  // paired bf16 (incl. ct)
                                              const int* __restrict__ rowptr,
                                              const int* __restrict__ ssrc,  // src*64, padded +128 zeros
                                              const unsigned short* __restrict__ eaA,  // [E+32][16] f16 rows
                                              const unsigned int* __restrict__ MtBl,   // [8][64][4] dwords f16 B-frags
                                              const float* __restrict__ att,
                                              const float* __restrict__ bias_o,
                                              const float* __restrict__ lng,
                                              const float* __restrict__ lnb,
                                              float* __restrict__ xout,
                                              unsigned short* __restrict__ xbf_out) {
  __shared__ float em2_s[2 * CHUNK * 66];  // [hi][row][slot], stride 66 dw
  int n = blockIdx.x;
  int l = threadIdx.x;  // lane 0..63
  int lm = l & 15, quad = l >> 4;
  int j0 = (l >> 3) * 16 + (l & 7), j1 = j0 + 8;

  // B fragments for this layer's Mt (f16), 8 channel-blocks, resident.
  uint4 bfr[8];
  const uint4* mb = (const uint4*)MtBl;
#pragma unroll
  for (int b = 0; b < 8; ++b) bfr[b] = mb[b * 64 + l];

  unsigned int ur = xrb[(size_t)n * 64 + l];
  f32x2 base;
  base.x = __uint_as_float(ur << 16);
  base.y = __uint_as_float(ur & 0xFFFF0000u);
  const float LOG2E = 1.44269504088896340736f;
  f32x2 attp = {att[j0] * LOG2E, att[j1] * LOG2E};
  f32x2 c02 = {0.2f, 0.2f};
  int beg = rowptr[n], end = rowptr[n + 1];

  f32x2 acc = {0.f, 0.f};
  float denom = 0.f;

  // per-lane scatter base: hi half + quad row-group + slot-within-8
  int ebase = (lm >> 3) * (CHUNK * 66) + (quad * 4) * 66 + (lm & 7);

  // chunk-level pipeline preload (padded buffers -> unconditional)
  half8 afz;
#pragma unroll
  for (int e2 = 0; e2 < 8; ++e2) afz[e2] = (_Float16)0.f;
  int sv = ssrc[beg + l];  // lane l holds src-row offset of edge beg+l
  half8 af = afz;
  if (quad < 2) af = *(const half8*)(eaA + (size_t)(beg + lm) * 16 + quad * 8);

  for (int c0 = beg; c0 < end; c0 += CHUNK) {
    int cnt = min(CHUNK, end - c0);
    // prefetch next chunk's sv + A-frag (wave-uniform gate: no overrun traffic)
    int sv_n = sv;
    half8 af_n = af;
    if (c0 + CHUNK < end) {
      sv_n = ssrc[c0 + CHUNK + l];
      af_n = afz;
      if (quad < 2) af_n = *(const half8*)(eaA + (size_t)(c0 + CHUNK + lm) * 16 + quad * 8);
    }

    // em[16 edges][128 ch] = ea @ Mt via MFMA (A row=edge, k=quad*8..+7;
    // quads 2,3 carry the zero pad in registers)
    f32x4 cc[8];
#pragma unroll
    for (int b = 0; b < 8; ++b)
      cc[b] = __builtin_amdgcn_mfma_f32_16x16x32_f16(af, *(half8*)&bfr[b], (f32x4)(0.f), 0, 0, 0);
    // scatter C into split-half LDS: one b32 store per (b,r), exact 2-way
#pragma unroll
    for (int b = 0; b < 8; ++b)
#pragma unroll
      for (int r = 0; r < 4; ++r)
        em2_s[ebase + r * 66 + b * 8] = cc[b][r];

    // uniform gather base for edge i (readlane -> SGPR; SALU addressing)
    auto srow = [&](int i) {
      return xlb + (unsigned int)__builtin_amdgcn_readlane(sv, i);
    };

    auto edge = [&](int i, unsigned int u) {
      f32x2 xls;
      xls.x = __uint_as_float(u << 16);
      xls.y = __uint_as_float(u & 0xFFFF0000u);
      f32x2 em;
      em.x = em2_s[i * 66 + l];               // ds_read_b32, stride-1: free
      em.y = em2_s[CHUNK * 66 + i * 66 + l];  // ds_read_b32, stride-1: free
      f32x2 m = pk_add(pk_add(base, xls), em);
      // leaky_relu(m, 0.2) = max(m, 0.2*m): packed mul + 2 scalar maxes
      f32x2 ms = pk_mul(c02, m);
      m.x = fmaxf(m.x, ms.x);
      m.y = fmaxf(m.y, ms.y);
      f32x2 v2 = pk_mul(m, attp);
      float vs = dpp_hadd8(v2.x + v2.y);  // head logit*log2e (8 lanes/head)
      float p = exp2f(vs);                // logits small: no max-subtract
      denom += p;
      acc.x = fmaf(xls.x, p, acc.x);
      acc.y = fmaf(xls.y, p, acc.y);
    };

    // depth-4 software pipeline, unconditional loads (sv spans 64 edges and
    // ssrc pad is zero -> indices up to 19 are always safe)
    unsigned int cur[4];
#pragma unroll
    for (int q = 0; q < 4; ++q) cur[q] = srow(q)[l];
    int cnt4 = cnt & ~3;
    for (int i = 0; i < cnt4; i += 4) {
      unsigned int nxt[4];
#pragma unroll
      for (int q = 0; q < 4; ++q) nxt[q] = srow(i + 4 + q)[l];
#pragma unroll
      for (int q = 0; q < 4; ++q) edge(i + q, cur[q]);
#pragma unroll
      for (int q = 0; q < 4; ++q) cur[q] = nxt[q];
    }
#pragma unroll
    for (int q = 0; q < 4; ++q)
      if (cnt4 + q < cnt) edge(cnt4 + q, cur[q]);

    sv = sv_n;
    af = af_n;
  }

  f32x2 outp;
  float inv = 1.f / (denom + 1e-16f);
  outp.x = acc.x * inv + bias_o[j0];
  outp.y = acc.y * inv + bias_o[j1];
  // LayerNorm over 128 channels: pair-sum then 64-lane butterfly (single wave)
  float s1 = outp.x + outp.y;
  float s2 = outp.x * outp.x + outp.y * outp.y;
#pragma unroll
  for (int mask = 1; mask <= 32; mask <<= 1) {
    s1 += __shfl_xor(s1, mask);
    s2 += __shfl_xor(s2, mask);
  }
  float mu = s1 * (1.f / 128.f);
  float var = s2 * (1.f / 128.f) - mu * mu;
  float rs = rsqrtf(var + 1e-5f);
  float y0 = lng[j0] * (outp.x - mu) * rs + lnb[j0];
  float y1 = lng[j1] * (outp.y - mu) * rs + lnb[j1];
  float r0 = fmaxf(y0, 0.f) + xin[(size_t)n * HID + j0];
  float r1 = fmaxf(y1, 0.f) + xin[(size_t)n * HID + j1];
  xout[(size_t)n * HID + j0] = r0;
  xout[(size_t)n * HID + j1] = r1;
  if (xbf_out) {  // skipped on last layer (nothing consumes it)
    xbf_out[(size_t)n * HID + j0] = f2bf(r0);
    xbf_out[(size_t)n * HID + j1] = f2bf(r1);
  }
}

extern "C" void kernel_launch(void* const* d_in, const int* in_sizes, int n_in,
                              void* d_out, int out_size, void* d_ws, size_t ws_size,
                              hipStream_t stream) {
  const float* x0    = (const float*)d_in[0];
  const int*   eidx  = (const int*)d_in[2];
  const float* eattr = (const float*)d_in[3];
  const float* Wt    = (const float*)d_in[4];
  const float* bt    = (const float*)d_in[5];
  const float* Wl    = (const float*)d_in[6];
  const float* bl    = (const float*)d_in[7];
  const float* Wr    = (const float*)d_in[8];
  const float* br    = (const float*)d_in[9];
  const float* We    = (const float*)d_in[10];
  const float* att   = (const float*)d_in[11];
  const float* bo    = (const float*)d_in[12];
  const float* lng   = (const float*)d_in[13];
  const float* lnb   = (const float*)d_in[14];
  float* out = (float*)d_out;
  const int* src = eidx;
  const int* dst = eidx + N_EDGES;

  char* ws = (char*)d_ws;
  size_t off = 0;
  auto alloc = [&](size_t bytes) {
    char* p = ws + off;
    off += (bytes + 255) & ~(size_t)255;
    return p;
  };
  int* counts = (int*)alloc((size_t)N_NODES * 4);
  int* eord   = (int*)alloc((size_t)N_EDGES * 4);
  float* ct   = (float*)alloc((size_t)NLAYERS * HID * 4);
  int* rowptr = (int*)alloc((size_t)(N_NODES + 1) * 4);
  int* bsum   = (int*)alloc(256 * 4);
  int* ssrc   = (int*)alloc(((size_t)N_EDGES + 128) * 4);
  unsigned short* eaA = (unsigned short*)alloc(((size_t)N_EDGES + 32) * 16 * 2);
  unsigned short* MtB = (unsigned short*)alloc((size_t)NLAYERS * 8 * 64 * 8 * 2);
  unsigned short* xlb = (unsigned short*)alloc((size_t)N_NODES * HID * 2);
  unsigned short* xrb = (unsigned short*)alloc((size_t)N_NODES * HID * 2);
  float* xbuf = (float*)alloc((size_t)N_NODES * HID * 4);
  unsigned short* xbf = (unsigned short*)alloc((size_t)N_NODES * HID * 2);
  unsigned short* WTb = (unsigned short*)alloc((size_t)NLAYERS * 2 * HID * HID * 2);

  hipMemsetAsync(counts, 0, (size_t)N_NODES * 4, stream);
  // zero ssrc pad (row 0 = safe gather target for pipeline overrun)
  hipMemsetAsync(ssrc + N_EDGES, 0, 128 * 4, stream);

  hipLaunchKernelGGL(k_setup, dim3(6035), dim3(256), 0, stream,
                     Wt, bt, We, Wl, Wr, x0, dst, counts, eord, ct, MtB, WTb, xbf);
  hipLaunchKernelGGL(k_scan1, dim3(SCAN_BLOCKS), dim3(256), 0, stream, counts, rowptr, bsum);
  hipLaunchKernelGGL(k_scan3, dim3(SCAN_BLOCKS), dim3(256), 0, stream, rowptr, bsum);
  hipLaunchKernelGGL(k_fill, dim3((N_EDGES + 255) / 256), dim3(256), 0, stream,
                     src, dst, rowptr, eord, ssrc, eattr, eaA);

  for (int l = 0; l < NLAYERS; ++l) {
    const float* xin = (l == 0) ? x0 : (const float*)xbuf;
    float* xout = (l == NLAYERS - 1) ? out : xbuf;
    unsigned short* xbf_next = (l == NLAYERS - 1) ? (unsigned short*)nullptr : xbf;
    hipLaunchKernelGGL(k_gemm_mfma, dim3((N_NODES + 63) / 64), dim3(256), 0, stream,
                       xbf, WTb + (size_t)l * 2 * HID * HID, bl + l * HID, br + l * HID,
                       ct + (size_t)l * HID, xlb, xrb);
    hipLaunchKernelGGL(k_fused, dim3(N_NODES), dim3(64), 0, stream,
                       xin, (const unsigned int*)xlb, (const unsigned int*)xrb,
                       rowptr, ssrc, eaA,
                       (const unsigned int*)(MtB + (size_t)l * 8 * 64 * 8),
                       att + l * HID,
                       bo + l * HID, lng + l * HID, lnb + l * HID, xout, xbf_next);
  }
}

// Round 15
// 401.664 us; speedup vs baseline: 1.0232x; 1.0232x over previous
//
#include <hip/hip_runtime.h>

#define N_NODES 50000
#define N_EDGES 640000
#define HID 128
#define EF 16
#define NLAYERS 3
#define CHUNK 16   // MFMA M-tile: 16 edges per chunk
#define SCAN_BLOCKS 196  // ceil(50000/256)

typedef __attribute__((ext_vector_type(8))) short short8;
typedef __attribute__((ext_vector_type(8))) _Float16 half8;
typedef __attribute__((ext_vector_type(4))) float f32x4;
typedef __attribute__((ext_vector_type(2))) float f32x2;

__device__ __forceinline__ unsigned short f2bf(float f) {
  unsigned int u = __float_as_uint(f);
  u = u + 0x7FFFu + ((u >> 16) & 1u);  // RNE
  return (unsigned short)(u >> 16);
}

__device__ __forceinline__ unsigned short f2h(float f) {
  _Float16 h = (_Float16)f;
  return *(unsigned short*)&h;
}

// 8-lane butterfly sum via DPP-FUSED adds (v_add_f32_dpp: permute on src0),
// 3 instructions instead of 6 (mov_dpp+add). s_nop 1 = 2 wait states covers
// the GFX9-lineage VALU-write -> DPP-read hazard (asm bypasses the compiler's
// hazard recognizer).
__device__ __forceinline__ float dpp_hadd8(float v) {
  asm("s_nop 1\n\t"
      "v_add_f32_dpp %0, %0, %0 quad_perm:[1,0,3,2] row_mask:0xf bank_mask:0xf bound_ctrl:0\n\t"
      "s_nop 1\n\t"
      "v_add_f32_dpp %0, %0, %0 quad_perm:[2,3,0,1] row_mask:0xf bank_mask:0xf bound_ctrl:0\n\t"
      "s_nop 1\n\t"
      "v_add_f32_dpp %0, %0, %0 row_half_mirror row_mask:0xf bank_mask:0xf bound_ctrl:0"
      : "+v"(v));
  return v;
}

__device__ __forceinline__ f32x2 pk_add(f32x2 a, f32x2 b) {
  f32x2 d;
  asm("v_pk_add_f32 %0, %1, %2" : "=v"(d) : "v"(a), "v"(b));
  return d;
}
__device__ __forceinline__ f32x2 pk_mul(f32x2 a, f32x2 b) {
  f32x2 d;
  asm("v_pk_mul_f32 %0, %1, %2" : "=v"(d) : "v"(a), "v"(b));
  return d;
}

// channel j = h*16+c -> paired slot: lane l = h*8 + (c&7) holds halves c>>3.
__device__ __forceinline__ int pslot(int j) {
  return (((j >> 4) * 8 + (j & 7)) << 1) + ((j >> 3) & 1);
}

// Fused setup: blocks [0,26) k_prep (MtB f16 fragments + ct), [26,410) cvtw,
// [410,3535) cvtx, [3535,6035) hist (dst-degree histogram + edge rank).
__global__ __launch_bounds__(256) void k_setup(const float* __restrict__ Wt,
                                               const float* __restrict__ bt,
                                               const float* __restrict__ We,
                                               const float* __restrict__ Wl,
                                               const float* __restrict__ Wr,
                                               const float* __restrict__ x,
                                               const int* __restrict__ dst,
                                               int* __restrict__ counts,
                                               int* __restrict__ eord,
                                               float* __restrict__ ct,
                                               unsigned short* __restrict__ MtB,
                                               unsigned short* __restrict__ WT,
                                               unsigned short* __restrict__ xbf) {
  int b = blockIdx.x, t = threadIdx.x;
  if (b < 26) {
    int id = b * 256 + t;
    const int total = NLAYERS * (EF + 1) * HID;
    if (id >= total) return;
    int l = id / ((EF + 1) * HID);
    int r = id % ((EF + 1) * HID);
    int row = r / HID;
    int j = r % HID;
    const float* Wel = We + l * HID * HID;
    float s = 0.f;
    if (row < EF) {
      const float* wtr = Wt + row * HID;
      for (int i = 0; i < HID; ++i) s += wtr[i] * Wel[i * HID + j];
      // MFMA B-fragment layout for mfma_f32_16x16x32_f16:
      // lane = (k>>3)*16 + n, elem = k&7; k in [0,32) (k>=16 zero-padded).
      int blk = j >> 4, nn = j & 15;
      size_t base = (size_t)(l * 8 + blk) * 64;
      MtB[(base + (size_t)((row >> 3) * 16 + nn)) * 8 + (row & 7)] = f2h(s);
      MtB[(base + (size_t)((2 + (row >> 3)) * 16 + nn)) * 8 + (row & 7)] = 0;
    } else {
      for (int i = 0; i < HID; ++i) s += bt[i] * Wel[i * HID + j];
      ct[l * HID + pslot(j)] = s;
    }
  } else if (b < 410) {
    int id = (b - 26) * 256 + t;  // exactly NLAYERS*2*128*128 = 98304
    int k = id & (HID - 1);
    int n = (id >> 7) & (HID - 1);
    int s = (id >> 14) & 1;
    int l = id >> 15;
    const float* W = (s == 0 ? Wl : Wr) + (size_t)l * HID * HID;
    WT[id] = f2bf(W[k * HID + n]);
  } else if (b < 3535) {
    int id = (b - 410) * 256 + t;  // exactly N_NODES*HID/8 = 800000
    const float4* p = (const float4*)(x + (size_t)id * 8);
    float4 a = p[0], bb = p[1];
    unsigned short o[8] = {f2bf(a.x), f2bf(a.y), f2bf(a.z), f2bf(a.w),
                           f2bf(bb.x), f2bf(bb.y), f2bf(bb.z), f2bf(bb.w)};
    *(uint4*)(xbf + (size_t)id * 8) = *(uint4*)o;
  } else {
    int e = (b - 3535) * 256 + t;  // exactly N_EDGES = 640000
    if (e < N_EDGES) {
      int pos = atomicAdd(&counts[dst[e]], 1);
      eord[e] = pos;  // edge's rank within its dst segment (order-free)
    }
  }
}

__global__ __launch_bounds__(256) void k_scan1(const int* __restrict__ counts,
                                               int* __restrict__ rowptr,
                                               int* __restrict__ bsum) {
  __shared__ int sc[256];
  int t = threadIdx.x;
  int i = blockIdx.x * 256 + t;
  int v = (i < N_NODES) ? counts[i] : 0;
  sc[t] = v;
  __syncthreads();
  for (int off = 1; off < 256; off <<= 1) {
    int u = 0;
    if (t >= off) u = sc[t - off];
    __syncthreads();
    sc[t] += u;
    __syncthreads();
  }
  if (i < N_NODES) rowptr[i] = sc[t] - v;  // block-local exclusive
  if (t == 255) bsum[blockIdx.x] = sc[255];
}

// scan2 folded in: every block redundantly scans the 196 block sums in LDS
// (cheap) -> eliminates the fully-serializing 1-block scan2 dispatch.
__global__ __launch_bounds__(256) void k_scan3(int* __restrict__ rowptr,
                                               const int* __restrict__ bsum) {
  __shared__ int sc[256];
  int t = threadIdx.x;
  int v = (t < SCAN_BLOCKS) ? bsum[t] : 0;
  sc[t] = v;
  __syncthreads();
  for (int off = 1; off < 256; off <<= 1) {
    int u = 0;
    if (t >= off) u = sc[t - off];
    __syncthreads();
    sc[t] += u;
    __syncthreads();
  }
  int b = blockIdx.x;
  int boff = (b == 0) ? 0 : sc[b - 1];  // exclusive offset for this block
  int i = b * 256 + t;
  if (i < N_NODES) rowptr[i] += boff;
  if (i == 0) rowptr[N_NODES] = N_EDGES;
}

// Scatter edges into dst-sorted order; idx = rowptr[dst] + precomputed rank
// (NO atomics). ssrc stores src*64 (dword row offset). Emits edge_attr as
// f16 rows: eaA[idx][0..15]=f16(ea).
__global__ __launch_bounds__(256) void k_fill(const int* __restrict__ src,
                                              const int* __restrict__ dst,
                                              const int* __restrict__ rowptr,
                                              const int* __restrict__ eord,
                                              int* __restrict__ ssrc,
                                              const float* __restrict__ eattr,
                                              unsigned short* __restrict__ eaA) {
  int e = blockIdx.x * 256 + threadIdx.x;
  if (e >= N_EDGES) return;
  int d = dst[e];
  int idx = rowptr[d] + eord[e];
  ssrc[idx] = src[e] << 6;
  const float* pe = eattr + (size_t)e * EF;
  unsigned short* po = eaA + (size_t)idx * 16;
#pragma unroll
  for (int g = 0; g < 2; ++g) {
    unsigned short o[8];
#pragma unroll
    for (int k = 0; k < 8; ++k) o[k] = f2h(pe[g * 8 + k]);
    *(uint4*)(po + g * 8) = *(uint4*)o;
  }
}

// bf16 MFMA node GEMM: out_s = x @ W_s + b_s for BOTH s in one block
// (As/xbf loaded once), channel-PAIRED layout, bf16 out. s=1 folds ct.
__global__ __launch_bounds__(256) void k_gemm_mfma(const unsigned short* __restrict__ xbf,
                                                   const unsigned short* __restrict__ WTl,
                                                   const float* __restrict__ bl,
                                                   const float* __restrict__ br,
                                                   const float* __restrict__ ctl,
                                                   unsigned short* __restrict__ xlb,
                                                   unsigned short* __restrict__ xrb) {
  __shared__ short As[64 * 136];
  __shared__ short Bs[128 * 136];
  int t = threadIdx.x;
  int row0 = blockIdx.x * 64;

  const uint4* gx = (const uint4*)xbf;
#pragma unroll
  for (int p = 0; p < 4; ++p) {
    int c = t + p * 256;
    int row = c >> 4, col16 = c & 15;
    int grow = row0 + row;
    if (grow >= N_NODES) grow = N_NODES - 1;
    uint4 v = gx[grow * 16 + col16];
    *(uint4*)(&As[row * 136 + col16 * 8]) = v;
  }

  int lane = t & 63, w = t >> 6;
  int quad = lane >> 4, lm = lane & 15;
  const uint4* gw = (const uint4*)WTl;

  for (int s = 0; s < 2; ++s) {
    if (s) __syncthreads();  // all waves done with previous Bs
#pragma unroll
    for (int p = 0; p < 8; ++p) {
      int c = t + p * 256;
      int row = c >> 4, col16 = c & 15;
      uint4 v = gw[s * 2048 + row * 16 + col16];
      *(uint4*)(&Bs[row * 136 + col16 * 8]) = v;
    }
    __syncthreads();  // Bs (and As on first iter) ready

    f32x4 acc[4][2];
#pragma unroll
    for (int mf = 0; mf < 4; ++mf)
#pragma unroll
      for (int nf = 0; nf < 2; ++nf) acc[mf][nf] = (f32x4)(0.f);

#pragma unroll
    for (int ks = 0; ks < 4; ++ks) {
      short8 af[4], bf[2];
#pragma unroll
      for (int mf = 0; mf < 4; ++mf)
        af[mf] = *(short8*)(&As[(mf * 16 + lm) * 136 + ks * 32 + quad * 8]);
#pragma unroll
      for (int nf = 0; nf < 2; ++nf)
        bf[nf] = *(short8*)(&Bs[(w * 32 + nf * 16 + lm) * 136 + ks * 32 + quad * 8]);
#pragma unroll
      for (int mf = 0; mf < 4; ++mf)
#pragma unroll
        for (int nf = 0; nf < 2; ++nf)
          acc[mf][nf] = __builtin_amdgcn_mfma_f32_16x16x32_bf16(af[mf], bf[nf], acc[mf][nf], 0, 0, 0);
    }

    const float* bias = (s == 0) ? bl : br;
    unsigned short* out = (s == 0) ? xlb : xrb;
#pragma unroll
    for (int nf = 0; nf < 2; ++nf) {
      int n = w * 32 + nf * 16 + lm;
      int slot = pslot(n);
      float bv = bias[n] + ((s == 1) ? ctl[slot] : 0.f);
#pragma unroll
      for (int mf = 0; mf < 4; ++mf) {
#pragma unroll
        for (int r = 0; r < 4; ++r) {
          int grow = row0 + mf * 16 + quad * 4 + r;
          if (grow < N_NODES) out[(size_t)grow * HID + slot] = f2bf(acc[mf][nf][r] + bv);
        }
      }
    }
  }
}

// ONE WAVE per destination node, barrier-free. Lane l owns channels
// j0=(l>>3)*16+(l&7), j0+8 (same head). Per 16-edge chunk, the ea@Mt edge
// embedding is computed on the MFMA pipe (8x mfma_f32_16x16x32_f16, K
// zero-padded 16->32 in registers) and scattered once into an LDS tile in
// paired-channel f32 layout; the edge loop costs 1 ds_read_b64 + 1 pk_add.
// NO src_s LDS: lane l keeps sv=ssrc[c0+l] in a register; per-edge broadcast
// via readlane -> uniform SGPR gather base (addressing on SALU pipe).
// Chunk-level pipeline: next chunk's sv + eaA A-frag prefetched under the
// current chunk's work, GATED on the wave-uniform "next chunk exists" test.
// Rolling depth-4 gather pipeline in the edge loop (best measured schedule).
__global__ __launch_bounds__(64) void k_fused(const float* __restrict__ xin,
                                              const unsigned int* __restrict__ xlb,  // paired bf16
                                              const unsigned int* __restrict__ xrb,  // paired bf16 (incl. ct)
                                              const int* __restrict__ rowptr,
                                              const int* __restrict__ ssrc,  // src*64, padded +128 zeros
                                              const unsigned short* __restrict__ eaA,  // [E+32][16] f16 rows
                                              const unsigned int* __restrict__ MtBl,   // [8][64][4] dwords f16 B-frags
                                              const float* __restrict__ att,
                                              const float* __restrict__ bias_o,
                                              const float* __restrict__ lng,
                                              const float* __restrict__ lnb,
                                              float* __restrict__ xout,
                                              unsigned short* __restrict__ xbf_out) {
  __shared__ __align__(16) float em_s[CHUNK * 130];  // paired-channel f32, row stride 130 dw
  int n = blockIdx.x;
  int l = threadIdx.x;  // lane 0..63
  int lm = l & 15, quad = l >> 4;
  int j0 = (l >> 3) * 16 + (l & 7), j1 = j0 + 8;

  // B fragments for this layer's Mt (f16), 8 channel-blocks, resident.
  uint4 bfr[8];
  const uint4* mb = (const uint4*)MtBl;
#pragma unroll
  for (int b = 0; b < 8; ++b) bfr[b] = mb[b * 64 + l];

  unsigned int ur = xrb[(size_t)n * 64 + l];
  f32x2 base;
  base.x = __uint_as_float(ur << 16);
  base.y = __uint_as_float(ur & 0xFFFF0000u);
  const float LOG2E = 1.44269504088896340736f;
  f32x2 attp = {att[j0] * LOG2E, att[j1] * LOG2E};
  f32x2 c02 = {0.2f, 0.2f};
  int beg = rowptr[n], end = rowptr[n + 1];

  f32x2 acc = {0.f, 0.f};
  float denom = 0.f;

  // chunk-level pipeline preload (padded buffers -> unconditional)
  half8 afz;
#pragma unroll
  for (int e2 = 0; e2 < 8; ++e2) afz[e2] = (_Float16)0.f;
  int sv = ssrc[beg + l];  // lane l holds src-row offset of edge beg+l
  half8 af = afz;
  if (quad < 2) af = *(const half8*)(eaA + (size_t)(beg + lm) * 16 + quad * 8);

  for (int c0 = beg; c0 < end; c0 += CHUNK) {
    int cnt = min(CHUNK, end - c0);
    // prefetch next chunk's sv + A-frag (wave-uniform gate: no overrun traffic)
    int sv_n = sv;
    half8 af_n = af;
    if (c0 + CHUNK < end) {
      sv_n = ssrc[c0 + CHUNK + l];
      af_n = afz;
      if (quad < 2) af_n = *(const half8*)(eaA + (size_t)(c0 + CHUNK + lm) * 16 + quad * 8);
    }

    // em[16 edges][128 ch] = ea @ Mt via MFMA (A row=edge, k=quad*8..+7;
    // quads 2,3 carry the zero pad in registers)
    f32x4 cc[8];
#pragma unroll
    for (int b = 0; b < 8; ++b)
      cc[b] = __builtin_amdgcn_mfma_f32_16x16x32_f16(af, *(half8*)&bfr[b], (f32x4)(0.f), 0, 0, 0);
    // scatter C into paired-channel LDS: row=quad*4+r, dword=2*pslot_pair+half
#pragma unroll
    for (int b = 0; b < 8; ++b)
#pragma unroll
      for (int r = 0; r < 4; ++r)
        em_s[(quad * 4 + r) * 130 + ((b * 8 + (lm & 7)) << 1) + (lm >> 3)] = cc[b][r];

    // uniform gather base for edge i (readlane -> SGPR; SALU addressing)
    auto srow = [&](int i) {
      return xlb + (unsigned int)__builtin_amdgcn_readlane(sv, i);
    };

    auto edge = [&](int i, unsigned int u) {
      f32x2 xls;
      xls.x = __uint_as_float(u << 16);
      xls.y = __uint_as_float(u & 0xFFFF0000u);
      f32x2 em = *(const f32x2*)(&em_s[i * 130 + 2 * l]);  // ds_read_b64
      f32x2 m = pk_add(pk_add(base, xls), em);
      // leaky_relu(m, 0.2) = max(m, 0.2*m): packed mul + 2 scalar maxes
      f32x2 ms = pk_mul(c02, m);
      m.x = fmaxf(m.x, ms.x);
      m.y = fmaxf(m.y, ms.y);
      f32x2 v2 = pk_mul(m, attp);
      float vs = dpp_hadd8(v2.x + v2.y);  // head logit*log2e (8 lanes/head)
      float p = exp2f(vs);                // logits small: no max-subtract
      denom += p;
      acc.x = fmaf(xls.x, p, acc.x);
      acc.y = fmaf(xls.y, p, acc.y);
    };

    // depth-4 software pipeline, unconditional loads (sv spans 64 edges and
    // ssrc pad is zero -> indices up to 19 are always safe)
    unsigned int cur[4];
#pragma unroll
    for (int q = 0; q < 4; ++q) cur[q] = srow(q)[l];
    int cnt4 = cnt & ~3;
    for (int i = 0; i < cnt4; i += 4) {
      unsigned int nxt[4];
#pragma unroll
      for (int q = 0; q < 4; ++q) nxt[q] = srow(i + 4 + q)[l];
#pragma unroll
      for (int q = 0; q < 4; ++q) edge(i + q, cur[q]);
#pragma unroll
      for (int q = 0; q < 4; ++q) cur[q] = nxt[q];
    }
#pragma unroll
    for (int q = 0; q < 4; ++q)
      if (cnt4 + q < cnt) edge(cnt4 + q, cur[q]);

    sv = sv_n;
    af = af_n;
  }

  f32x2 outp;
  float inv = 1.f / (denom + 1e-16f);
  outp.x = acc.x * inv + bias_o[j0];
  outp.y = acc.y * inv + bias_o[j1];
  // LayerNorm over 128 channels: pair-sum then 64-lane butterfly (single wave)
  float s1 = outp.x + outp.y;
  float s2 = outp.x * outp.x + outp.y * outp.y;
#pragma unroll
  for (int mask = 1; mask <= 32; mask <<= 1) {
    s1 += __shfl_xor(s1, mask);
    s2 += __shfl_xor(s2, mask);
  }
  float mu = s1 * (1.f / 128.f);
  float var = s2 * (1.f / 128.f) - mu * mu;
  float rs = rsqrtf(var + 1e-5f);
  float y0 = lng[j0] * (outp.x - mu) * rs + lnb[j0];
  float y1 = lng[j1] * (outp.y - mu) * rs + lnb[j1];
  float r0 = fmaxf(y0, 0.f) + xin[(size_t)n * HID + j0];
  float r1 = fmaxf(y1, 0.f) + xin[(size_t)n * HID + j1];
  xout[(size_t)n * HID + j0] = r0;
  xout[(size_t)n * HID + j1] = r1;
  if (xbf_out) {  // skipped on last layer (nothing consumes it)
    xbf_out[(size_t)n * HID + j0] = f2bf(r0);
    xbf_out[(size_t)n * HID + j1] = f2bf(r1);
  }
}

extern "C" void kernel_launch(void* const* d_in, const int* in_sizes, int n_in,
                              void* d_out, int out_size, void* d_ws, size_t ws_size,
                              hipStream_t stream) {
  const float* x0    = (const float*)d_in[0];
  const int*   eidx  = (const int*)d_in[2];
  const float* eattr = (const float*)d_in[3];
  const float* Wt    = (const float*)d_in[4];
  const float* bt    = (const float*)d_in[5];
  const float* Wl    = (const float*)d_in[6];
  const float* bl    = (const float*)d_in[7];
  const float* Wr    = (const float*)d_in[8];
  const float* br    = (const float*)d_in[9];
  const float* We    = (const float*)d_in[10];
  const float* att   = (const float*)d_in[11];
  const float* bo    = (const float*)d_in[12];
  const float* lng   = (const float*)d_in[13];
  const float* lnb   = (const float*)d_in[14];
  float* out = (float*)d_out;
  const int* src = eidx;
  const int* dst = eidx + N_EDGES;

  char* ws = (char*)d_ws;
  size_t off = 0;
  auto alloc = [&](size_t bytes) {
    char* p = ws + off;
    off += (bytes + 255) & ~(size_t)255;
    return p;
  };
  int* counts = (int*)alloc((size_t)N_NODES * 4);
  int* eord   = (int*)alloc((size_t)N_EDGES * 4);
  float* ct   = (float*)alloc((size_t)NLAYERS * HID * 4);
  int* rowptr = (int*)alloc((size_t)(N_NODES + 1) * 4);
  int* bsum   = (int*)alloc(256 * 4);
  int* ssrc   = (int*)alloc(((size_t)N_EDGES + 128) * 4);
  unsigned short* eaA = (unsigned short*)alloc(((size_t)N_EDGES + 32) * 16 * 2);
  unsigned short* MtB = (unsigned short*)alloc((size_t)NLAYERS * 8 * 64 * 8 * 2);
  unsigned short* xlb = (unsigned short*)alloc((size_t)N_NODES * HID * 2);
  unsigned short* xrb = (unsigned short*)alloc((size_t)N_NODES * HID * 2);
  float* xbuf = (float*)alloc((size_t)N_NODES * HID * 4);
  unsigned short* xbf = (unsigned short*)alloc((size_t)N_NODES * HID * 2);
  unsigned short* WTb = (unsigned short*)alloc((size_t)NLAYERS * 2 * HID * HID * 2);

  hipMemsetAsync(counts, 0, (size_t)N_NODES * 4, stream);
  // zero ssrc pad (row 0 = safe gather target for pipeline overrun)
  hipMemsetAsync(ssrc + N_EDGES, 0, 128 * 4, stream);

  hipLaunchKernelGGL(k_setup, dim3(6035), dim3(256), 0, stream,
                     Wt, bt, We, Wl, Wr, x0, dst, counts, eord, ct, MtB, WTb, xbf);
  hipLaunchKernelGGL(k_scan1, dim3(SCAN_BLOCKS), dim3(256), 0, stream, counts, rowptr, bsum);
  hipLaunchKernelGGL(k_scan3, dim3(SCAN_BLOCKS), dim3(256), 0, stream, rowptr, bsum);
  hipLaunchKernelGGL(k_fill, dim3((N_EDGES + 255) / 256), dim3(256), 0, stream,
                     src, dst, rowptr, eord, ssrc, eattr, eaA);

  for (int l = 0; l < NLAYERS; ++l) {
    const float* xin = (l == 0) ? x0 : (const float*)xbuf;
    float* xout = (l == NLAYERS - 1) ? out : xbuf;
    unsigned short* xbf_next = (l == NLAYERS - 1) ? (unsigned short*)nullptr : xbf;
    hipLaunchKernelGGL(k_gemm_mfma, dim3((N_NODES + 63) / 64), dim3(256), 0, stream,
                       xbf, WTb + (size_t)l * 2 * HID * HID, bl + l * HID, br + l * HID,
                       ct + (size_t)l * HID, xlb, xrb);
    hipLaunchKernelGGL(k_fused, dim3(N_NODES), dim3(64), 0, stream,
                       xin, (const unsigned int*)xlb, (const unsigned int*)xrb,
                       rowptr, ssrc, eaA,
                       (const unsigned int*)(MtB + (size_t)l * 8 * 64 * 8),
                       att + l * HID,
                       bo + l * HID, lng + l * HID, lnb + l * HID, xout, xbf_next);
  }
}